// Round 8
// baseline (137.195 us; speedup 1.0000x reference)
//
#include <hip/hip_runtime.h>

// (B,N,D,L) = (32,1000,256,3), all fp32. d_in: [0]=x (unused),
// [1]=node_feature, [2]=Ws (L,D,D), [3]=bs (L,D).
// Math collapses (A_norm = ones/N):
//   h[b,:] = MLP(mean_n nf[b,n,:]);  out0 = nf + h (broadcast);  out1 = nf.
//
// R7 post-mortem: 6 graph nodes => ~10 us dispatch/gap overhead each dominated.
// This round: 3 launches. k_zero folded into k_colsum (direct partial writes,
// no atomics); the 3 per-layer GEMVs fused into one 32-block kernel where
// thread t owns output column d=t across all layers (no cross-thread reduce).
#define BB 32
#define NN 1000
#define DD 256
#define SS 25              // node-axis splits for the column mean
#define RPS 40             // rows per split; SS*RPS == NN
#define ELEMS (BB * NN * DD)   // 8,192,000 floats per output tensor

// ---- Kernel 1: partial column sums over the node axis, float4 loads ----
// grid (SS, BB), 256 thr. Thread t: row-in-group = t>>6 (4 rows), f4-col = t&63.
// Writes partial[(s*BB+b)*DD + t] directly (no zero pass, no atomics).
__global__ __launch_bounds__(256) void k_colsum(const float* __restrict__ nf,
                                                float* __restrict__ partial) {
    const int s = blockIdx.x, b = blockIdx.y, t = threadIdx.x;
    const int rg = t >> 6, dg = t & 63;
    const float4* src = (const float4*)nf;          // DD/4 = 64 float4 per row
    float4 acc = make_float4(0.f, 0.f, 0.f, 0.f);
#pragma unroll
    for (int c = 0; c < RPS / 4; c++) {             // 10 iters of 4 rows
        const int n = s * RPS + c * 4 + rg;
        float4 v = src[(b * NN + n) * (DD / 4) + dg];
        acc.x += v.x; acc.y += v.y; acc.z += v.z; acc.w += v.w;
    }
    __shared__ float red[1024];
    ((float4*)red)[rg * 64 + dg] = acc;             // red[rg*256 + dg*4 + j]
    __syncthreads();
    float sum = 0.f;
#pragma unroll
    for (int r = 0; r < 4; r++) sum += red[r * 256 + t];  // thread t owns d == t
    partial[(s * BB + b) * DD + t] = sum;
}

// ---- Kernel 2: fused mean + 3-layer MLP. 32 blocks (one per batch), 256 thr.
// Thread t owns output column d=t: per layer, 64 iters of {broadcast h4 from
// LDS, 4 coalesced W column loads, 4 fmacs}. No cross-thread reduce.
__global__ __launch_bounds__(256) void k_mlp(const float* __restrict__ partial,
                                             const float* __restrict__ Ws,
                                             const float* __restrict__ bsv,
                                             float* __restrict__ hrow) {
    const int b = blockIdx.x, t = threadIdx.x;
    __shared__ float h[DD];
    // mean over nodes: reduce SS partials (coalesced, stride BB*DD)
    float sum = 0.f;
#pragma unroll 5
    for (int s = 0; s < SS; s++) sum += partial[(s * BB + b) * DD + t];
    h[t] = sum * (1.0f / (float)NN);
    __syncthreads();
    for (int l = 0; l < 3; l++) {
        const float* W = Ws + l * DD * DD;          // W[k][d], row-major
        float acc = 0.f;
#pragma unroll 8
        for (int k4 = 0; k4 < DD / 4; k4++) {       // 64 iters
            const float4 hv = ((const float4*)h)[k4];   // LDS broadcast read
            const int k = k4 * 4;
            acc += hv.x * W[(k + 0) * DD + t];      // coalesced across t
            acc += hv.y * W[(k + 1) * DD + t];
            acc += hv.z * W[(k + 2) * DD + t];
            acc += hv.w * W[(k + 3) * DD + t];
        }
        float o = acc + bsv[l * DD + t];
        if (l < 2) o = fmaxf(o, 0.f);
        __syncthreads();            // all reads of h done before overwrite
        h[t] = o;
        __syncthreads();
    }
    hrow[b * DD + t] = h[t];
}

// ---- Kernel 3: out0 = nf + broadcast(h), out1 = nf. float4 everywhere. ----
__global__ __launch_bounds__(256) void k_out(const float* __restrict__ nf,
                                             const float* __restrict__ hrow,
                                             float* __restrict__ out) {
    const int i = blockIdx.x * 256 + threadIdx.x;   // float4-chunk id, 2,048,000
    const int e = i * 4;                            // flat float index
    const int b = e / (NN * DD);
    const int d0 = e & (DD - 1);                    // multiple of 4
    float4 v = ((const float4*)nf)[i];
    float4 hv = *(const float4*)(hrow + b * DD + d0);
    float4 o = make_float4(v.x + hv.x, v.y + hv.y, v.z + hv.z, v.w + hv.w);
    ((float4*)out)[i] = o;                          // output 0
    ((float4*)(out + ELEMS))[i] = v;                // output 1
}

extern "C" void kernel_launch(void* const* d_in, const int* in_sizes, int n_in,
                              void* d_out, int out_size, void* d_ws, size_t ws_size,
                              hipStream_t stream) {
    const float* nf  = (const float*)d_in[1];   // node_feature
    const float* Ws  = (const float*)d_in[2];   // (L,D,D)
    const float* bsv = (const float*)d_in[3];   // (L,D)
    float* out = (float*)d_out;

    float* partial = (float*)d_ws;              // SS*BB*DD = 204,800 floats
    float* hrow    = partial + SS * BB * DD;    // BB*DD    =   8,192 floats

    k_colsum<<<dim3(SS, BB), 256, 0, stream>>>(nf, partial);
    k_mlp<<<BB, 256, 0, stream>>>(partial, Ws, bsv, hrow);
    k_out<<<(ELEMS / 4) / 256, 256, 0, stream>>>(nf, hrow, out);
}

// Round 9
// 134.877 us; speedup vs baseline: 1.0172x; 1.0172x over previous
//
#include <hip/hip_runtime.h>

// (B,N,D,L) = (32,1000,256,3), all fp32. d_in: [0]=x (unused),
// [1]=node_feature, [2]=Ws (L,D,D), [3]=bs (L,D).
// Math collapses (A_norm = ones/N):
//   h[b,:] = MLP(mean_n nf[b,n,:]);  out0 = nf + h (broadcast);  out1 = nf.
//
// R8 post-mortem: 32-block fused MLP was latency-bound (R6 redux); launch
// overhead is minor. This round: TWO 256-block kernels, no cross-block sync.
//   A: stream nf -> out1 + per-block column partials (pure stores).
//   B: every block redundantly computes its batch's 3-layer MLP from the 8
//      partials (W is L2-shared per XCD; redundancy costs no wall time),
//      then writes out0 for its own 125-row slice (nf re-read is L2/L3-warm,
//      same block->slice mapping as A for XCD affinity).
#define BB 32
#define NN 1000
#define DD 256
#define ELEMS (BB * NN * DD)   // 8,192,000 floats per output tensor
#define SLICES 8               // blocks per batch
#define ROWS 125               // rows per block; SLICES*ROWS == NN
#define F4S (ROWS * DD / 4)    // 8000 float4 per slice

// ---- Kernel A: out1 = nf, plus per-block column sums ----
// grid 256 = (batch b = j>>3, slice s = j&7). Thread t: fixed f4-col (t&63),
// row-group t>>6; 32 strided iters over the slice.
__global__ __launch_bounds__(256) void k_stage(const float* __restrict__ nf,
                                               float* __restrict__ out1,
                                               float* __restrict__ partial) {
    const int j = blockIdx.x, t = threadIdx.x;
    const int b = j >> 3, s = j & 7;
    const int base = (b * NN + s * ROWS) * (DD / 4);     // float4 index
    const float4* src = (const float4*)nf;
    float4* dst = (float4*)out1;
    float4 acc = make_float4(0.f, 0.f, 0.f, 0.f);
#pragma unroll 4
    for (int idx = t; idx < F4S; idx += 256) {           // col = idx&63 == t&63
        float4 v = src[base + idx];
        dst[base + idx] = v;
        acc.x += v.x; acc.y += v.y; acc.z += v.z; acc.w += v.w;
    }
    __shared__ float red[1024];
    ((float4*)red)[(t >> 6) * 64 + (t & 63)] = acc;      // red[rg*256 + d]
    __syncthreads();
    float sum = 0.f;
#pragma unroll
    for (int r = 0; r < 4; r++) sum += red[r * 256 + t]; // thread t owns d == t
    partial[j * DD + t] = sum;
}

// ---- Kernel B: redundant per-block MLP + out0 = nf + broadcast(h) ----
__global__ __launch_bounds__(256) void k_mlp_out(const float* __restrict__ nf,
                                                 const float* __restrict__ partial,
                                                 const float* __restrict__ Ws,
                                                 const float* __restrict__ bsv,
                                                 float* __restrict__ out0) {
    const int j = blockIdx.x, t = threadIdx.x;
    const int b = j >> 3, s = j & 7;
    __shared__ float h[DD];
    // mean over nodes: sum this batch's 8 partial vectors (8 KB, coalesced)
    float m = 0.f;
#pragma unroll
    for (int i = 0; i < SLICES; i++) m += partial[(b * SLICES + i) * DD + t];
    h[t] = m * (1.0f / (float)NN);
    __syncthreads();
    // 3-layer MLP; thread t owns output column d=t; W loads coalesced across t
    for (int l = 0; l < 3; l++) {
        const float* W = Ws + l * DD * DD;               // W[k][d], row-major
        float acc = 0.f;
#pragma unroll 8
        for (int k4 = 0; k4 < DD / 4; k4++) {            // 64 iters, LDS broadcast
            const float4 hv = ((const float4*)h)[k4];
            const int k = k4 * 4;
            acc += hv.x * W[(k + 0) * DD + t];
            acc += hv.y * W[(k + 1) * DD + t];
            acc += hv.z * W[(k + 2) * DD + t];
            acc += hv.w * W[(k + 3) * DD + t];
        }
        float o = acc + bsv[l * DD + t];
        if (l < 2) o = fmaxf(o, 0.f);
        __syncthreads();                                 // h reads done
        h[t] = o;
        __syncthreads();
    }
    // out0 for this block's slice; same addresses as kernel A => XCD L2 affinity
    const int base = (b * NN + s * ROWS) * (DD / 4);
    const float4 hv = ((const float4*)h)[t & 63];        // col fixed per thread
    const float4* src = (const float4*)nf;
    float4* dst = (float4*)out0;
#pragma unroll 4
    for (int idx = t; idx < F4S; idx += 256) {
        float4 v = src[base + idx];
        dst[base + idx] = make_float4(v.x + hv.x, v.y + hv.y, v.z + hv.z, v.w + hv.w);
    }
}

extern "C" void kernel_launch(void* const* d_in, const int* in_sizes, int n_in,
                              void* d_out, int out_size, void* d_ws, size_t ws_size,
                              hipStream_t stream) {
    const float* nf  = (const float*)d_in[1];   // node_feature
    const float* Ws  = (const float*)d_in[2];   // (L,D,D)
    const float* bsv = (const float*)d_in[3];   // (L,D)
    float* out0 = (float*)d_out;                // floats [0, 8.192M)
    float* out1 = out0 + ELEMS;                 // floats [8.192M, 16.384M)

    float* partial = (float*)d_ws;              // 256*DD = 65,536 floats

    k_stage<<<BB * SLICES, 256, 0, stream>>>(nf, out1, partial);
    k_mlp_out<<<BB * SLICES, 256, 0, stream>>>(nf, partial, Ws, bsv, out0);
}